// Round 11
// baseline (105.278 us; speedup 1.0000x reference)
//
#include <hip/hip_runtime.h>
#include <hip/hip_bf16.h>

// Problem constants (match reference)
#define CIN_  128
#define H_    28
#define W_    28
#define COUT_ 32
#define B_    512
// GEMM view per (b,h): Y[32 x 28] = Wm[32 x 384] * Xwin[384 x 28]
// K order: kappa = tap*128 + channel, chunked in 12 chunks of 32.

typedef __attribute__((ext_vector_type(8))) short short8;  // 8 bf16 in 4 VGPRs
typedef __attribute__((ext_vector_type(4))) float f32x4;

__device__ __forceinline__ unsigned short f2bfu(float f) {
    union { __hip_bfloat16 h; unsigned short s; } u;
    u.h = __float2bfloat16(f);                 // RNE, single HW cvt
    return u.s;
}
__device__ __forceinline__ short f2bf(float f) { return (short)f2bfu(f); }

// ---------------------------------------------------------------------------
// Pre-pass: build bf16 A-fragments of Wm in d_ws.
// Fragment f = mt*12 + kc  (mt: 0..1 M-tile of 16 couts, kc: 0..11 K-chunk of 32)
// Element (lane l, slot j): Wm[jo = mt*16 + (l&15)][i = (kc&3)*32 + (l>>4)*8 + j][tap = kc>>2]
// Stored flat: ws[f*512 + l*8 + j]  -> lane l loads 16B at f*1024 + l*16 bytes.
// ---------------------------------------------------------------------------
__global__ void prep_w_kernel(const float* __restrict__ w, short* __restrict__ wsA) {
    int t = blockIdx.x * 256 + threadIdx.x;      // 24*512 = 12288 threads
    int frag = t >> 9;
    int rem  = t & 511;
    int l = rem >> 3;
    int j = rem & 7;
    int mt = frag / 12;
    int kc = frag % 12;
    int tap = kc >> 2;
    int i  = (kc & 3) * 32 + (l >> 4) * 8 + j;
    int jo = mt * 16 + (l & 15);
    wsA[t] = f2bf(w[(jo * CIN_ + i) * 3 + tap]);
}

// ---------------------------------------------------------------------------
// Main kernel v11: PERSISTENT WHOLE-BATCH blocks, single generation.
// grid 512 x 256 threads (4 waves); exactly 2 blocks/CU, all resident for the
// whole kernel -> no generational convoy. Block b owns x[b] and out[b]: every
// HBM line read/written by exactly one block (no cross-block RMW/over-fetch).
// 14 iterations of 2 rows each, double-buffered (4 row-bufs: bi = (g&1)*2+hl).
// Per iteration g (rows 2g, 2g+1):
//   1. cvt + packed-b32 scatter of vb -> bufs[(g&1)*2 + hl]
//   2. prefetch group g+1 into vb (loads stay in flight across the barrier)
//   3. lgkmcnt(0); raw s_barrier     (NO vmcnt drain - the key to overlap)
//   4. per-wave GEMM: wave wv -> row r = wv>>1, M-half mt = wv&1
//      (persistent per-wave A-frags: only 12 = 48 VGPR, spill-proof)
//   5. scalar dword stores with roll
// LDS row-buf layout (int units, buffer bi):
//   word(wt, cpair) at  wt*64 + (((cpair>>2) ^ (wt&15) ^ bi) & 15) << 2 | (cpair&3)
// Read side: B-frag chunk cch of row wtc = b128 at short index
//   wtc*128 + (((cch ^ (wtc&15) ^ bi) & 15) << 3)
// wt = w + tap (w_real = wt-1). Rows 0,29 zeroed once (staging never touches
// them). B-reads with wt in 30..33 feed discarded cols (wcol >= 28); clamp
// to 29. LDS-reuse safety: buffer parity p is re-written at iteration g+2;
// iteration g+1's lgkmcnt(0)+barrier guarantees every wave's GEMM-g ds_reads
// are complete before any wave stages g+2.
// ---------------------------------------------------------------------------
template<bool USE_WS>
__global__ __launch_bounds__(256, 3)
void conv_kernel(const float* __restrict__ x, const float* __restrict__ w,
                 const short* __restrict__ wsA, float* __restrict__ out) {
    __shared__ short lds[4][30 * CIN_];          // 4 x 7680 B = 30720 B
    const int tid = threadIdx.x;
    const int wv  = tid >> 6;
    const int l   = tid & 63;
    const int r   = wv >> 1;                     // row within 2-row group
    const int mt  = wv & 1;                      // M-half (16 couts)
    const int b   = blockIdx.x;

    const float* xb = x + (size_t)b * (CIN_ * H_ * W_);
    float*       ob = out + (size_t)b * (COUT_ * H_ * W_);

    // ---- zero pad rows wt=0 and wt=29 in all 4 buffers (once) ----
    {
        int idx = tid * 2;                       // int index 0..510
        int bi  = idx >> 7;                      // 0..3
        int wrd = idx & 127;
        int row = (wrd >> 6) ? 29 : 0;
        int ci  = wrd & 63;
        *reinterpret_cast<ulong1*>(
            reinterpret_cast<int*>(&lds[bi][0]) + row * 64 + ci) = ulong1{0};
    }

    // ---- group-0 loads: channel-pair c, slot q (hl = q/7, w4 = q%7) ----
    f32x4 v0[4], v1[4];
#pragma unroll
    for (int it = 0; it < 4; ++it) {
        int s = it * 256 + tid;                  // 0..1023, valid < 896
        if (s < 896) {
            int c = s / 14, q = s % 14;
            int hl = q / 7, w4 = q % 7;
            const float* p = xb + (2 * c) * (H_ * W_) + hl * W_ + w4 * 4;
            v0[it] = *reinterpret_cast<const f32x4*>(p);
            v1[it] = *reinterpret_cast<const f32x4*>(p + H_ * W_);
        }
    }

    // ---- persistent per-wave A-fragments (12 = 48 VGPR, this wave's mt) ----
    short8 af[12];
    if (USE_WS) {
#pragma unroll
        for (int kc = 0; kc < 12; ++kc)
            af[kc] = *reinterpret_cast<const short8*>(wsA + (mt * 12 + kc) * 512 + l * 8);
    } else {
#pragma unroll
        for (int kc = 0; kc < 12; ++kc) {
            int tap = kc >> 2;
            int ib  = (kc & 3) * 32 + (l >> 4) * 8;
#pragma unroll
            for (int j = 0; j < 8; ++j)
                af[kc][j] = f2bf(w[((mt * 16 + (l & 15)) * CIN_ + ib + j) * 3 + tap]);
        }
    }

#pragma unroll 2
    for (int g = 0; g < 14; ++g) {
        const int par = g & 1;

        // ---- 1. cvt + packed-b32 scatter vb -> LDS ----
#pragma unroll
        for (int it = 0; it < 4; ++it) {
            int s = it * 256 + tid;
            if (s < 896) {
                int c = s / 14, q = s % 14;
                int hl = q / 7, w4 = q % 7;
                int bi = par * 2 + hl;
                int* buf = reinterpret_cast<int*>(&lds[bi][0]);
#pragma unroll
                for (int e = 0; e < 4; ++e) {
                    int wt  = w4 * 4 + e + 1;    // 1..28
                    int idx = wt * 64 + (((((c >> 2) ^ (wt & 15) ^ bi) & 15) << 2) | (c & 3));
                    unsigned word = (unsigned)f2bfu(v0[it][e]) |
                                    ((unsigned)f2bfu(v1[it][e]) << 16);
                    buf[idx] = (int)word;
                }
            }
        }

        // ---- 2. prefetch group g+1 (in flight across the barrier) ----
        if (g < 13) {
            const int h0n = (g + 1) * 2;
#pragma unroll
            for (int it = 0; it < 4; ++it) {
                int s = it * 256 + tid;
                if (s < 896) {
                    int c = s / 14, q = s % 14;
                    int hl = q / 7, w4 = q % 7;
                    const float* p = xb + (2 * c) * (H_ * W_) + (h0n + hl) * W_ + w4 * 4;
                    v0[it] = *reinterpret_cast<const f32x4*>(p);
                    v1[it] = *reinterpret_cast<const f32x4*>(p + H_ * W_);
                }
            }
            __builtin_amdgcn_sched_barrier(0);
        }

        // ---- 3. raw barrier: ds_writes visible, prefetch NOT drained ----
        asm volatile("s_waitcnt lgkmcnt(0)" ::: "memory");
        __builtin_amdgcn_sched_barrier(0);
        __builtin_amdgcn_s_barrier();
        __builtin_amdgcn_sched_barrier(0);

        // ---- 4. per-wave GEMM: row r, M-half mt ----
        const int bi = par * 2 + r;
        short* wbuf = &lds[bi][0];
        f32x4 acc[2];
#pragma unroll
        for (int q = 0; q < 4; ++q) { acc[0][q] = 0.0f; acc[1][q] = 0.0f; }

#pragma unroll
        for (int kc = 0; kc < 12; ++kc) {
            int tap = kc >> 2;
            int cch = (kc & 3) * 4 + (l >> 4);   // chunk of lane's 8 channels
#pragma unroll
            for (int nt = 0; nt < 2; ++nt) {
                int wt  = nt * 16 + (l & 15) + tap;   // 0..33
                int wtc = wt > 29 ? 29 : wt;          // rows >29 feed dead cols
                const short8 bfrag = *reinterpret_cast<const short8*>(
                    &wbuf[wtc * CIN_ + ((((cch ^ (wtc & 15) ^ bi) & 15)) << 3)]);
                acc[nt] = __builtin_amdgcn_mfma_f32_16x16x32_bf16(
                    af[kc], bfrag, acc[nt], 0, 0, 0);
            }
        }

        // ---- 5. store with roll: y row h -> out row (h+1)%28 ----
        {
            const int h  = g * 2 + r;
            const int ho = (h + 1 == H_) ? 0 : (h + 1);
#pragma unroll
            for (int nt = 0; nt < 2; ++nt) {
                int wcol = nt * 16 + (l & 15);
                if (wcol < W_) {
#pragma unroll
                    for (int rr = 0; rr < 4; ++rr) {
                        int j = mt * 16 + (l >> 4) * 4 + rr;
                        ob[(j * H_ + ho) * W_ + wcol] = acc[nt][rr];
                    }
                }
            }
        }
    }
}

extern "C" void kernel_launch(void* const* d_in, const int* in_sizes, int n_in,
                              void* d_out, int out_size, void* d_ws, size_t ws_size,
                              hipStream_t stream) {
    (void)in_sizes; (void)n_in; (void)out_size;
    const float* x = (const float*)d_in[0];
    const float* w = (const float*)d_in[1];
    float* out = (float*)d_out;

    if (ws_size >= (size_t)(24 * 512 * sizeof(short))) {
        short* wsA = (short*)d_ws;
        prep_w_kernel<<<dim3(48), dim3(256), 0, stream>>>(w, wsA);
        conv_kernel<true><<<dim3(B_), dim3(256), 0, stream>>>(x, w, wsA, out);
    } else {
        conv_kernel<false><<<dim3(B_), dim3(256), 0, stream>>>(x, w, (const short*)nullptr, out);
    }
}

// Round 12
// 73.588 us; speedup vs baseline: 1.4306x; 1.4306x over previous
//
#include <hip/hip_runtime.h>
#include <hip/hip_bf16.h>

// Problem constants (match reference)
#define CIN_  128
#define H_    28
#define W_    28
#define COUT_ 32
#define B_    512
// GEMM view per (b,h): Y[32 x 28] = Wm[32 x 384] * Xwin[384 x 28]
// K order: kappa = tap*128 + channel, chunked in 12 chunks of 32.

typedef __attribute__((ext_vector_type(8))) short short8;  // 8 bf16 in 4 VGPRs
typedef __attribute__((ext_vector_type(4))) float f32x4;

__device__ __forceinline__ unsigned short f2bfu(float f) {
    union { __hip_bfloat16 h; unsigned short s; } u;
    u.h = __float2bfloat16(f);                 // RNE, single HW cvt
    return u.s;
}
__device__ __forceinline__ short f2bf(float f) { return (short)f2bfu(f); }

// ---------------------------------------------------------------------------
// Pre-pass: build bf16 A-fragments of Wm in d_ws.
// Fragment f = mt*12 + kc  (mt: 0..1 M-tile of 16 couts, kc: 0..11 K-chunk of 32)
// Element (lane l, slot j): Wm[jo = mt*16 + (l&15)][i = (kc&3)*32 + (l>>4)*8 + j][tap = kc>>2]
// Stored flat: ws[f*512 + l*8 + j]  -> lane l loads 16B at f*1024 + l*16 bytes.
// ---------------------------------------------------------------------------
__global__ void prep_w_kernel(const float* __restrict__ w, short* __restrict__ wsA) {
    int t = blockIdx.x * 256 + threadIdx.x;      // 24*512 = 12288 threads
    int frag = t >> 9;
    int rem  = t & 511;
    int l = rem >> 3;
    int j = rem & 7;
    int mt = frag / 12;
    int kc = frag % 12;
    int tap = kc >> 2;
    int i  = (kc & 3) * 32 + (l >> 4) * 8 + j;
    int jo = mt * 16 + (l & 15);
    wsA[t] = f2bf(w[(jo * CIN_ + i) * 3 + tap]);
}

// ---------------------------------------------------------------------------
// Main kernel v12 = R9 (best, 55.7us) + XCD-bijective swizzle ONLY + NT hints.
// grid 3584 x 256 threads (4 waves). Swizzle: L = (Bid&7)*448 + (Bid>>3),
// b = L/7, hg = L%7 -> all 7 hg-blocks of a batch (and 64 consecutive b)
// share one XCD's L2: the roll-offset output lines (112-B rows vs 128-B
// lines) split between adjacent-hg blocks now merge in ONE L2 instead of
// RMW-bouncing between XCDs; x boundary lines likewise fetched once.
// x loads and out stores are non-temporal (read-once / write-once streams):
// keeps L2 for wsA + write-combining, avoids polluting with 200 MB of x.
// Staging: thread owns (channel-pair c, w-quad q): two coalesced f32x4 NT
// loads; the pair packs into one b32 LDS word (28 writes + 28 pk-cvts).
// LDS word layout (int units, row-buffer hl):
//   word(wt, c) at  wt*64 + (((c>>2) ^ (wt&15) ^ hl) << 2 | (c&3))
// (hl-XOR term spreads the 4 row-buffers across bank-quads: ~2-way residual
// conflict on staging writes instead of ~8-way.)
// Read side (wave wv = hl): B-frag chunk cch of row wtc is the b128 at short
// index  wtc*128 + ((cch ^ (wtc&15) ^ wv) << 3)  - conflict-free.
// wt = w + tap (w_real = wt-1). Rows 0 and 29 zeroed (padding). B-reads with
// wt in 30..33 only feed discarded output cols (wcol >= 28); clamp to 29.
// A-frag half-0 loads issued BEFORE __syncthreads (barrier's vmcnt drain
// completes them for free).
// ---------------------------------------------------------------------------
template<bool USE_WS>
__global__ __launch_bounds__(256, 5)
void conv_kernel(const float* __restrict__ x, const float* __restrict__ w,
                 const short* __restrict__ wsA, float* __restrict__ out) {
    __shared__ short lds[4][30 * CIN_];          // 4 x 7680 B = 30720 B
    const int tid = threadIdx.x;
    const int wv  = tid >> 6;
    const int l   = tid & 63;

    // ---- XCD-bijective block swizzle (nwg = 3584 = 8 * 448) ----
    const int Bid = blockIdx.x;
    const int L   = (Bid & 7) * 448 + (Bid >> 3);
    const int b   = L / 7;                       // 0..511
    const int hg  = L % 7;                       // 0..6
    const int h0  = hg * 4;

    const float* xb = x + (size_t)b * (CIN_ * H_ * W_);

    // ---- zero pad rows wt=0 and wt=29 in this wave's buffer ----
    {
        int s   = (tid & 63) * 4;                // 0..252
        int row = (s >= 128) ? 29 : 0;
        int c   = s & 127;
        *reinterpret_cast<ulong1*>(&lds[wv][row * CIN_ + c]) = ulong1{0};
    }

    // ---- staging loads (non-temporal): 64 ch-pairs x 28 quads ----
    f32x4 v0[7], v1[7];
#pragma unroll
    for (int it = 0; it < 7; ++it) {
        int f4 = it * 256 + tid;                 // 0..1791
        int c  = f4 / 28;                        // channel pair 0..63
        int q  = f4 % 28;                        // quad within 448-B segment
        const f32x4* p = reinterpret_cast<const f32x4*>(
            xb + (2 * c) * (H_ * W_) + h0 * W_ + q * 4);
        v0[it] = __builtin_nontemporal_load(p);
        v1[it] = __builtin_nontemporal_load(
            reinterpret_cast<const f32x4*>(
                reinterpret_cast<const float*>(p) + H_ * W_));
    }

    // ---- packed cvt + b32 scatter into LDS (hl-aware swizzle) ----
#pragma unroll
    for (int it = 0; it < 7; ++it) {
        int f4 = it * 256 + tid;
        int c  = f4 / 28;
        int q  = f4 % 28;
        int hl = q / 7;                          // local row 0..3
        int w4 = q % 7;
        int* buf = reinterpret_cast<int*>(&lds[hl][0]);
#pragma unroll
        for (int e = 0; e < 4; ++e) {
            int wt  = w4 * 4 + e + 1;            // 1..28
            int idx = wt * 64 + ((((c >> 2) ^ (wt & 15) ^ hl) << 2) | (c & 3));
            unsigned word = (unsigned)f2bfu(v0[it][e]) |
                            ((unsigned)f2bfu(v1[it][e]) << 16);
            buf[idx] = (int)word;
        }
    }

    // ---- A fragments, first K-half: ISSUE before the barrier ----
    short8 a0[6], a1[6];
    if (USE_WS) {
#pragma unroll
        for (int k6 = 0; k6 < 6; ++k6) {
            a0[k6] = *reinterpret_cast<const short8*>(wsA + k6 * 512 + l * 8);
            a1[k6] = *reinterpret_cast<const short8*>(wsA + (12 + k6) * 512 + l * 8);
        }
    } else {
#pragma unroll
        for (int k6 = 0; k6 < 6; ++k6) {
            int tap = k6 >> 2;
            int ib  = (k6 & 3) * 32 + (l >> 4) * 8;
#pragma unroll
            for (int j = 0; j < 8; ++j) {
                a0[k6][j] = f2bf(w[((l & 15) * CIN_ + ib + j) * 3 + tap]);
                a1[k6][j] = f2bf(w[((16 + (l & 15)) * CIN_ + ib + j) * 3 + tap]);
            }
        }
    }
    __syncthreads();   // drains lgkm (staging) AND vmcnt (a-frags) for free

    // ---- per-wave GEMM: 2 M-tiles x 2 N-tiles x 12 K-chunks of 32 ----
    short* wbuf = lds[wv];
    const int h = h0 + wv;

    f32x4 acc[2][2];
#pragma unroll
    for (int mt = 0; mt < 2; ++mt)
#pragma unroll
        for (int nt = 0; nt < 2; ++nt)
#pragma unroll
            for (int q = 0; q < 4; ++q) acc[mt][nt][q] = 0.0f;

#pragma unroll
    for (int half = 0; half < 2; ++half) {
        if (half == 1) {                         // reload A frags, second K-half
            if (USE_WS) {
#pragma unroll
                for (int k6 = 0; k6 < 6; ++k6) {
                    int kc = 6 + k6;
                    a0[k6] = *reinterpret_cast<const short8*>(wsA + kc * 512 + l * 8);
                    a1[k6] = *reinterpret_cast<const short8*>(wsA + (12 + kc) * 512 + l * 8);
                }
            } else {
#pragma unroll
                for (int k6 = 0; k6 < 6; ++k6) {
                    int kc  = 6 + k6;
                    int tap = kc >> 2;
                    int ib  = (kc & 3) * 32 + (l >> 4) * 8;
#pragma unroll
                    for (int j = 0; j < 8; ++j) {
                        a0[k6][j] = f2bf(w[((l & 15) * CIN_ + ib + j) * 3 + tap]);
                        a1[k6][j] = f2bf(w[((16 + (l & 15)) * CIN_ + ib + j) * 3 + tap]);
                    }
                }
            }
        }
#pragma unroll
        for (int k6 = 0; k6 < 6; ++k6) {
            int kc  = half * 6 + k6;
            int tap = kc >> 2;
            int cch = (kc & 3) * 4 + (l >> 4);   // chunk index of lane's 8 channels
#pragma unroll
            for (int nt = 0; nt < 2; ++nt) {
                int wt  = nt * 16 + (l & 15) + tap;     // 0..33
                int wtc = wt > 29 ? 29 : wt;            // clamp: rows >29 feed dead cols
                const short8 bfrag = *reinterpret_cast<const short8*>(
                    &wbuf[wtc * CIN_ + ((cch ^ (wtc & 15) ^ wv) << 3)]);
                acc[0][nt] = __builtin_amdgcn_mfma_f32_16x16x32_bf16(
                    a0[k6], bfrag, acc[0][nt], 0, 0, 0);
                acc[1][nt] = __builtin_amdgcn_mfma_f32_16x16x32_bf16(
                    a1[k6], bfrag, acc[1][nt], 0, 0, 0);
            }
        }
    }

    // ---- store with roll (non-temporal): y row h -> out row (h+1)%28 ----
    float* ob = out + (size_t)b * (COUT_ * H_ * W_);
    const int ho = (h + 1 == H_) ? 0 : (h + 1);
#pragma unroll
    for (int mt = 0; mt < 2; ++mt)
#pragma unroll
        for (int nt = 0; nt < 2; ++nt)
#pragma unroll
            for (int rr = 0; rr < 4; ++rr) {
                int j    = mt * 16 + (l >> 4) * 4 + rr;
                int wcol = nt * 16 + (l & 15);
                if (wcol < W_)
                    __builtin_nontemporal_store(
                        acc[mt][nt][rr], ob + (j * H_ + ho) * W_ + wcol);
            }
}

extern "C" void kernel_launch(void* const* d_in, const int* in_sizes, int n_in,
                              void* d_out, int out_size, void* d_ws, size_t ws_size,
                              hipStream_t stream) {
    (void)in_sizes; (void)n_in; (void)out_size;
    const float* x = (const float*)d_in[0];
    const float* w = (const float*)d_in[1];
    float* out = (float*)d_out;

    if (ws_size >= (size_t)(24 * 512 * sizeof(short))) {
        short* wsA = (short*)d_ws;
        prep_w_kernel<<<dim3(48), dim3(256), 0, stream>>>(w, wsA);
        conv_kernel<true><<<dim3(3584), dim3(256), 0, stream>>>(x, w, wsA, out);
    } else {
        conv_kernel<false><<<dim3(3584), dim3(256), 0, stream>>>(x, w, (const short*)nullptr, out);
    }
}

// Round 13
// 57.616 us; speedup vs baseline: 1.8272x; 1.2772x over previous
//
#include <hip/hip_runtime.h>
#include <hip/hip_bf16.h>

// Problem constants (match reference)
#define CIN_  128
#define H_    28
#define W_    28
#define COUT_ 32
#define B_    512
// GEMM view per (b,h): Y[32 x 28] = Wm[32 x 384] * Xwin[384 x 28]
// K order: kappa = tap*128 + channel, chunked in 12 chunks of 32.

typedef __attribute__((ext_vector_type(8))) short short8;  // 8 bf16 in 4 VGPRs
typedef __attribute__((ext_vector_type(4))) float f32x4;

__device__ __forceinline__ unsigned short f2bfu(float f) {
    union { __hip_bfloat16 h; unsigned short s; } u;
    u.h = __float2bfloat16(f);                 // RNE, single HW cvt
    return u.s;
}
__device__ __forceinline__ short f2bf(float f) { return (short)f2bfu(f); }

// ---------------------------------------------------------------------------
// Pre-pass: build bf16 A-fragments of Wm in d_ws.
// Fragment f = mt*12 + kc  (mt: 0..1 M-tile of 16 couts, kc: 0..11 K-chunk of 32)
// Element (lane l, slot j): Wm[jo = mt*16 + (l&15)][i = (kc&3)*32 + (l>>4)*8 + j][tap = kc>>2]
// Stored flat: ws[f*512 + l*8 + j]  -> lane l loads 16B at f*1024 + l*16 bytes.
// ---------------------------------------------------------------------------
__global__ void prep_w_kernel(const float* __restrict__ w, short* __restrict__ wsA) {
    int t = blockIdx.x * 256 + threadIdx.x;      // 24*512 = 12288 threads
    int frag = t >> 9;
    int rem  = t & 511;
    int l = rem >> 3;
    int j = rem & 7;
    int mt = frag / 12;
    int kc = frag % 12;
    int tap = kc >> 2;
    int i  = (kc & 3) * 32 + (l >> 4) * 8 + j;
    int jo = mt * 16 + (l & 15);
    wsA[t] = f2bf(w[(jo * CIN_ + i) * 3 + tap]);
}

// ---------------------------------------------------------------------------
// Main kernel v13 = exact R9 (measured optimum, 55.7 us).
// grid (7, 512), block 256 (4 waves). Wave wv computes row h = hg*4 + wv.
// Staging: thread owns (channel-pair c = 2ch/2ch+1, w-quad q): two coalesced
// f32x4 loads; the pair packs into one b32 LDS word.
// LDS word layout (int units, within row-buffer hl):
//   word(wt, c) at  wt*64 + (((c>>2) ^ (wt&15) ^ hl) << 2 | (c&3))
// The ^hl term spreads the 4 row-buffers across bank-quads: without it, all
// hl and the w4-repetition (4*w4 mod 8 in {0,4}) pile ~8 lanes per bank on
// every staging write (~2.9x cost per m136). With it: counts 4,4,4,4,3,3,3,3
// over the 8 bank-quads -> ~2-way residual (free).
// Read side (wave wv = hl): B-frag chunk cch (8 channels) of row wtc is the
// b128 at short index  wtc*128 + ((cch ^ (wtc&15) ^ wv) << 3).
// wt = w + tap (w_real = wt-1). Rows 0 and 29 zeroed (padding). B-reads with
// wt in 30..33 only feed discarded output cols (wcol >= 28); clamp to 29.
// A-frag half-0 loads are issued BEFORE __syncthreads: the barrier's vmcnt
// drain completes them for free, removing L2 latency from the post-barrier
// critical path (vb registers are dead by then -> no added pressure).
// ---------------------------------------------------------------------------
template<bool USE_WS>
__global__ __launch_bounds__(256, 5)
void conv_kernel(const float* __restrict__ x, const float* __restrict__ w,
                 const short* __restrict__ wsA, float* __restrict__ out) {
    __shared__ short lds[4][30 * CIN_];          // 4 x 7680 B = 30720 B
    const int tid = threadIdx.x;
    const int wv  = tid >> 6;
    const int l   = tid & 63;
    const int hg  = blockIdx.x;                  // 0..6
    const int b   = blockIdx.y;                  // 0..511
    const int h0  = hg * 4;

    const float* xb = x + (size_t)b * (CIN_ * H_ * W_);

    // ---- zero pad rows wt=0 and wt=29 in this wave's buffer ----
    {
        int s   = (tid & 63) * 4;                // 0..252
        int row = (s >= 128) ? 29 : 0;
        int c   = s & 127;
        *reinterpret_cast<ulong1*>(&lds[wv][row * CIN_ + c]) = ulong1{0};
    }

    // ---- staging loads: 64 channel-pairs x 28 quads; 2 f32x4 per thread-iter
    f32x4 v0[7], v1[7];
#pragma unroll
    for (int it = 0; it < 7; ++it) {
        int f4 = it * 256 + tid;                 // 0..1791
        int c  = f4 / 28;                        // channel pair 0..63
        int q  = f4 % 28;                        // quad within 448-B segment
        const float* p = xb + (2 * c) * (H_ * W_) + h0 * W_ + q * 4;
        v0[it] = *reinterpret_cast<const f32x4*>(p);
        v1[it] = *reinterpret_cast<const f32x4*>(p + H_ * W_);
    }

    // ---- packed cvt + b32 scatter into LDS (hl-aware swizzle) ----
#pragma unroll
    for (int it = 0; it < 7; ++it) {
        int f4 = it * 256 + tid;
        int c  = f4 / 28;
        int q  = f4 % 28;
        int hl = q / 7;                          // local row 0..3
        int w4 = q % 7;
        int* buf = reinterpret_cast<int*>(&lds[hl][0]);
#pragma unroll
        for (int e = 0; e < 4; ++e) {
            int wt  = w4 * 4 + e + 1;            // 1..28
            int idx = wt * 64 + ((((c >> 2) ^ (wt & 15) ^ hl) << 2) | (c & 3));
            unsigned word = (unsigned)f2bfu(v0[it][e]) |
                            ((unsigned)f2bfu(v1[it][e]) << 16);
            buf[idx] = (int)word;
        }
    }

    // ---- A fragments, first K-half: ISSUE before the barrier ----
    short8 a0[6], a1[6];
    if (USE_WS) {
#pragma unroll
        for (int k6 = 0; k6 < 6; ++k6) {
            a0[k6] = *reinterpret_cast<const short8*>(wsA + k6 * 512 + l * 8);
            a1[k6] = *reinterpret_cast<const short8*>(wsA + (12 + k6) * 512 + l * 8);
        }
    } else {
#pragma unroll
        for (int k6 = 0; k6 < 6; ++k6) {
            int tap = k6 >> 2;
            int ib  = (k6 & 3) * 32 + (l >> 4) * 8;
#pragma unroll
            for (int j = 0; j < 8; ++j) {
                a0[k6][j] = f2bf(w[((l & 15) * CIN_ + ib + j) * 3 + tap]);
                a1[k6][j] = f2bf(w[((16 + (l & 15)) * CIN_ + ib + j) * 3 + tap]);
            }
        }
    }
    __syncthreads();   // drains lgkm (staging) AND vmcnt (a-frags) for free

    // ---- per-wave GEMM: 2 M-tiles x 2 N-tiles x 12 K-chunks of 32 ----
    short* wbuf = lds[wv];
    const int h = h0 + wv;

    f32x4 acc[2][2];
#pragma unroll
    for (int mt = 0; mt < 2; ++mt)
#pragma unroll
        for (int nt = 0; nt < 2; ++nt)
#pragma unroll
            for (int q = 0; q < 4; ++q) acc[mt][nt][q] = 0.0f;

#pragma unroll
    for (int half = 0; half < 2; ++half) {
        if (half == 1) {                         // reload A frags, second K-half
            if (USE_WS) {
#pragma unroll
                for (int k6 = 0; k6 < 6; ++k6) {
                    int kc = 6 + k6;
                    a0[k6] = *reinterpret_cast<const short8*>(wsA + kc * 512 + l * 8);
                    a1[k6] = *reinterpret_cast<const short8*>(wsA + (12 + kc) * 512 + l * 8);
                }
            } else {
#pragma unroll
                for (int k6 = 0; k6 < 6; ++k6) {
                    int kc  = 6 + k6;
                    int tap = kc >> 2;
                    int ib  = (kc & 3) * 32 + (l >> 4) * 8;
#pragma unroll
                    for (int j = 0; j < 8; ++j) {
                        a0[k6][j] = f2bf(w[((l & 15) * CIN_ + ib + j) * 3 + tap]);
                        a1[k6][j] = f2bf(w[((16 + (l & 15)) * CIN_ + ib + j) * 3 + tap]);
                    }
                }
            }
        }
#pragma unroll
        for (int k6 = 0; k6 < 6; ++k6) {
            int kc  = half * 6 + k6;
            int tap = kc >> 2;
            int cch = (kc & 3) * 4 + (l >> 4);   // chunk index of lane's 8 channels
#pragma unroll
            for (int nt = 0; nt < 2; ++nt) {
                int wt  = nt * 16 + (l & 15) + tap;     // 0..33
                int wtc = wt > 29 ? 29 : wt;            // clamp: rows >29 feed dead cols
                const short8 bfrag = *reinterpret_cast<const short8*>(
                    &wbuf[wtc * CIN_ + ((cch ^ (wtc & 15) ^ wv) << 3)]);
                acc[0][nt] = __builtin_amdgcn_mfma_f32_16x16x32_bf16(
                    a0[k6], bfrag, acc[0][nt], 0, 0, 0);
                acc[1][nt] = __builtin_amdgcn_mfma_f32_16x16x32_bf16(
                    a1[k6], bfrag, acc[1][nt], 0, 0, 0);
            }
        }
    }

    // ---- store with roll: y row h -> out row (h+1)%28 ----
    float* ob = out + (size_t)b * (COUT_ * H_ * W_);
    const int ho = (h + 1 == H_) ? 0 : (h + 1);
#pragma unroll
    for (int mt = 0; mt < 2; ++mt)
#pragma unroll
        for (int nt = 0; nt < 2; ++nt)
#pragma unroll
            for (int rr = 0; rr < 4; ++rr) {
                int j    = mt * 16 + (l >> 4) * 4 + rr;
                int wcol = nt * 16 + (l & 15);
                if (wcol < W_)
                    ob[(j * H_ + ho) * W_ + wcol] = acc[mt][nt][rr];
            }
}

extern "C" void kernel_launch(void* const* d_in, const int* in_sizes, int n_in,
                              void* d_out, int out_size, void* d_ws, size_t ws_size,
                              hipStream_t stream) {
    (void)in_sizes; (void)n_in; (void)out_size;
    const float* x = (const float*)d_in[0];
    const float* w = (const float*)d_in[1];
    float* out = (float*)d_out;

    if (ws_size >= (size_t)(24 * 512 * sizeof(short))) {
        short* wsA = (short*)d_ws;
        prep_w_kernel<<<dim3(48), dim3(256), 0, stream>>>(w, wsA);
        conv_kernel<true><<<dim3(7, 512), dim3(256), 0, stream>>>(x, w, wsA, out);
    } else {
        conv_kernel<false><<<dim3(7, 512), dim3(256), 0, stream>>>(x, w, (const short*)nullptr, out);
    }
}